// Round 6
// baseline (536.731 us; speedup 1.0000x reference)
//
#include <hip/hip_runtime.h>

#define SEQ    2048
#define DIM    2048              // D == N
#define NBATCH 4
#define MTOT   (NBATCH * SEQ)    // 8192
#define CHUNKS 32
#define CLEN   (SEQ / CHUNKS)    // 64
#define CSH    5                 // log2(CHUNKS)
#define HT_ELEMS (256 * 32)      // one staged K-half tile: 256 rows x 32 cols (16 KB)

typedef __bf16 bf16_t;
typedef __bf16 bf16x8 __attribute__((ext_vector_type(8)));
typedef float  f32x4  __attribute__((ext_vector_type(4)));
typedef unsigned short u16x4 __attribute__((ext_vector_type(4)));
typedef unsigned short u16x2 __attribute__((ext_vector_type(2)));

typedef __attribute__((address_space(3))) bf16_t lds_bf16;

__device__ __forceinline__ unsigned short f2bf_rne(float f) {
    unsigned int u = __float_as_uint(f);
    u += 0x7fffu + ((u >> 16) & 1u);
    return (unsigned short)(u >> 16);
}
__device__ __forceinline__ float bf2f(unsigned short v) {
    return __uint_as_float((unsigned int)v << 16);
}

// ---------------- fp32 -> bf16 convert ----------------
__global__ void k_convert(const float* __restrict__ src,
                          unsigned short* __restrict__ dst, int n4) {
    int i = blockIdx.x * blockDim.x + threadIdx.x;
    if (i >= n4) return;
    f32x4 v = ((const f32x4*)src)[i];
    u16x4 o;
    o[0] = f2bf_rne(v[0]); o[1] = f2bf_rne(v[1]);
    o[2] = f2bf_rne(v[2]); o[3] = f2bf_rne(v[3]);
    ((u16x4*)dst)[i] = o;
}

// convert + interleave: src row n -> dst row 2n+phase
__global__ void k_convert_ilv(const float* __restrict__ src,
                              unsigned short* __restrict__ dst, int n4, int phase) {
    int i = blockIdx.x * blockDim.x + threadIdx.x;
    if (i >= n4) return;
    const int R4 = DIM / 4;
    int nrow = i / R4;
    int dcol = i - nrow * R4;
    f32x4 v = ((const f32x4*)src)[i];
    u16x4 o;
    o[0] = f2bf_rne(v[0]); o[1] = f2bf_rne(v[1]);
    o[2] = f2bf_rne(v[2]); o[3] = f2bf_rne(v[3]);
    ((u16x4*)dst)[(2 * nrow + phase) * R4 + dcol] = o;
}

// negA[n] = -exp(A_log[n])
__global__ void k_prep_a(const float* __restrict__ A_log, float* __restrict__ negA, int n) {
    int i = blockIdx.x * blockDim.x + threadIdx.x;
    if (i < n) negA[i] = -__expf(A_log[i]);
}

// ---------------- staging: 16B global_load_lds, XOR-swizzled chunks ----------
__device__ __forceinline__ void stage_half(const bf16_t* __restrict__ g, long rowbase,
                                           int K, int k0, bf16_t* lds,
                                           int wave, int lane) {
    const int rl     = lane >> 2;
    const int gchunk = (lane & 3) ^ ((lane >> 3) & 3);
#pragma unroll
    for (int q = 0; q < 2; q++) {
        const bf16_t* ga = g + (rowbase + wave * 32 + q * 16 + rl) * (long)K
                             + k0 + gchunk * 8;
        __builtin_amdgcn_global_load_lds(
            (const __attribute__((address_space(1))) void*)ga,
            (__attribute__((address_space(3))) void*)((char*)lds + (wave * 32 + q * 16) * 64),
            16, 0, 0);
    }
}

#define MFMA_B16(a, b, c) __builtin_amdgcn_mfma_f32_16x16x32_bf16(a, b, c, 0, 0, 0)
#define BAR  __builtin_amdgcn_s_barrier()
#define SBAR __builtin_amdgcn_sched_barrier(0)
#define DSR(D, P) asm volatile("ds_read_b128 %0, %1" : "=v"(D) : "v"(P))
#define PRIO1 __builtin_amdgcn_s_setprio(1)
#define PRIO0 __builtin_amdgcn_s_setprio(0)
// wait for PREVIOUS phase's reads (issued a full phase ago -> near-free)
#define WAIT0 do { asm volatile("s_waitcnt lgkmcnt(0)"); SBAR; } while (0)
#define ENDPH do { SBAR; BAR; } while (0)

// ---------------- GEMM core: 256x256, BK=64, 8-phase + register read-ahead --
// 8 waves (2M x 4N), 512 threads, 128 KiB LDS, 1 block/CU.
// KEY FIX (m218 applied to lgkm): fragments are DOUBLE-BUFFERED in registers;
// phase p issues ds_reads for phase p+1 and computes on registers loaded at
// p-1. The LDS port drains UNDER the MFMA cluster; lgkmcnt(0) at phase entry
// waits reads that are a full phase old (near-free). One barrier per phase.
// Staging rotation (unchanged): P1:A11 P2:B00 P3:A00 P4:B01 P5:A01 P6:B10
// P7:A10 P8:B11. Read-ahead confirm points (counted vmcnt, 4-6 phase slack):
//   end-P1 needs <=A01(P5p)  end-P3 needs <=A10(P7p)
//   end-P5 needs <=A11(P1)   end-P7 needs <=A00(P3)   -> vmcnt(8) each.
template <int KTILES>   // number of 64-wide K tiles (K/64), must be even
__device__ __forceinline__ void gemm256_main(const bf16_t* __restrict__ A,
                                             const bf16_t* __restrict__ Bm,
                                             int K, long arow0, long brow0,
                                             bf16_t* As, bf16_t* Bs,
                                             f32x4 acc[8][4],
                                             int wave, int lane, int wm, int wn) {
    const int l15  = lane & 15;
    const int quad = lane >> 4;
    const int swz  = (quad ^ ((l15 >> 1) & 3)) * 8;
    const int aoff = (wm * 128 + l15) * 32 + swz;
    const int boff = (wn * 64  + l15) * 32 + swz;

    const lds_bf16* Aw = ((const lds_bf16*)As) + aoff;
    const lds_bf16* Bw = ((const lds_bf16*)Bs) + boff;

    auto stA = [&](int buf, int ks, int kt) {
        stage_half(A, arow0, K, kt * 64 + ks * 32, As + (buf * 2 + ks) * HT_ELEMS, wave, lane);
    };
    auto stB = [&](int buf, int ks, int kt) {
        stage_half(Bm, brow0, K, kt * 64 + ks * 32, Bs + (buf * 2 + ks) * HT_ELEMS, wave, lane);
    };

    // double-buffered fragment sets: aA/aB alternate per phase, b0/b1 per pair
    bf16x8 aA0, aA1, aA2, aA3, aB0, aB1, aB2, aB3;
    bf16x8 b00, b01, b02, b03, b10, b11, b12, b13;

#define RD_FULL(BUF, KS, A0, A1, A2, A3, B0, B1, B2, B3) { \
    const lds_bf16* pa = Aw + ((BUF) * 2 + (KS)) * HT_ELEMS; \
    const lds_bf16* pb = Bw + ((BUF) * 2 + (KS)) * HT_ELEMS; \
    DSR(A0, pa);        DSR(B0, pb); \
    DSR(A1, pa + 512);  DSR(B1, pb + 512); \
    DSR(A2, pa + 1024); DSR(B2, pb + 1024); \
    DSR(A3, pa + 1536); DSR(B3, pb + 1536); }
#define RD_HALF(BUF, KS, A0, A1, A2, A3) { \
    const lds_bf16* pa = Aw + ((BUF) * 2 + (KS)) * HT_ELEMS + 2048; \
    DSR(A0, pa); DSR(A1, pa + 512); DSR(A2, pa + 1024); DSR(A3, pa + 1536); }
#define MM16(I0, A0, A1, A2, A3, B0, B1, B2, B3) do { \
    PRIO1; \
    acc[(I0)+0][0] = MFMA_B16(A0, B0, acc[(I0)+0][0]); \
    acc[(I0)+0][1] = MFMA_B16(A0, B1, acc[(I0)+0][1]); \
    acc[(I0)+0][2] = MFMA_B16(A0, B2, acc[(I0)+0][2]); \
    acc[(I0)+0][3] = MFMA_B16(A0, B3, acc[(I0)+0][3]); \
    acc[(I0)+1][0] = MFMA_B16(A1, B0, acc[(I0)+1][0]); \
    acc[(I0)+1][1] = MFMA_B16(A1, B1, acc[(I0)+1][1]); \
    acc[(I0)+1][2] = MFMA_B16(A1, B2, acc[(I0)+1][2]); \
    acc[(I0)+1][3] = MFMA_B16(A1, B3, acc[(I0)+1][3]); \
    acc[(I0)+2][0] = MFMA_B16(A2, B0, acc[(I0)+2][0]); \
    acc[(I0)+2][1] = MFMA_B16(A2, B1, acc[(I0)+2][1]); \
    acc[(I0)+2][2] = MFMA_B16(A2, B2, acc[(I0)+2][2]); \
    acc[(I0)+2][3] = MFMA_B16(A2, B3, acc[(I0)+2][3]); \
    acc[(I0)+3][0] = MFMA_B16(A3, B0, acc[(I0)+3][0]); \
    acc[(I0)+3][1] = MFMA_B16(A3, B1, acc[(I0)+3][1]); \
    acc[(I0)+3][2] = MFMA_B16(A3, B2, acc[(I0)+3][2]); \
    acc[(I0)+3][3] = MFMA_B16(A3, B3, acc[(I0)+3][3]); \
    PRIO0; } while (0)

    // prologue: stage ALL 8 kt0/kt1 slots, drain once, pre-read P1's frags.
    stB(0, 0, 0); stA(0, 0, 0); stB(0, 1, 0); stA(0, 1, 0);
    stB(1, 0, 1); stA(1, 0, 1); stB(1, 1, 1); stA(1, 1, 1);
    asm volatile("s_waitcnt vmcnt(0)");
    SBAR;
    BAR;
    RD_FULL(0, 0, aA0, aA1, aA2, aA3, b00, b01, b02, b03);

#pragma unroll 1
    for (int t = 0; t < KTILES / 2; ++t) {
        const bool nlast = (t != KTILES / 2 - 1);
        const int k1 = 2 * t + 1, k2 = 2 * t + 2, k3 = 2 * t + 3;

        // P1: compute (aA,b0) rows0-3; read half(0,0)->aB; stage A11(k1) t>0
        WAIT0;
        RD_HALF(0, 0, aB0, aB1, aB2, aB3);
        if (t) stA(1, 1, k1);
        SBAR; asm volatile("s_waitcnt vmcnt(8)"); SBAR;
        MM16(0, aA0, aA1, aA2, aA3, b00, b01, b02, b03);
        ENDPH;
        // P2: compute (aB,b0) rows4-7; read full(0,1)->aA,b1; stage B00(k2)
        WAIT0;
        RD_FULL(0, 1, aA0, aA1, aA2, aA3, b10, b11, b12, b13);
        if (nlast) stB(0, 0, k2);
        SBAR;
        MM16(4, aB0, aB1, aB2, aB3, b00, b01, b02, b03);
        ENDPH;
        // P3: compute (aA,b1) rows0-3; read half(0,1)->aB; stage A00(k2)
        WAIT0;
        RD_HALF(0, 1, aB0, aB1, aB2, aB3);
        if (nlast) stA(0, 0, k2);
        SBAR;
        if (nlast) { asm volatile("s_waitcnt vmcnt(8)"); }
        else       { asm volatile("s_waitcnt vmcnt(4)"); }
        SBAR;
        MM16(0, aA0, aA1, aA2, aA3, b10, b11, b12, b13);
        ENDPH;
        // P4: compute (aB,b1) rows4-7; read full(1,0)->aA,b0; stage B01(k2)
        WAIT0;
        RD_FULL(1, 0, aA0, aA1, aA2, aA3, b00, b01, b02, b03);
        if (nlast) stB(0, 1, k2);
        SBAR;
        MM16(4, aB0, aB1, aB2, aB3, b10, b11, b12, b13);
        ENDPH;
        // P5: compute (aA,b0) rows0-3; read half(1,0)->aB; stage A01(k2)
        WAIT0;
        RD_HALF(1, 0, aB0, aB1, aB2, aB3);
        if (nlast) stA(0, 1, k2);
        SBAR;
        if (nlast) { asm volatile("s_waitcnt vmcnt(8)"); }
        else       { asm volatile("s_waitcnt vmcnt(0)"); }
        SBAR;
        MM16(0, aA0, aA1, aA2, aA3, b00, b01, b02, b03);
        ENDPH;
        // P6: compute (aB,b0) rows4-7; read full(1,1)->aA,b1; stage B10(k3)
        WAIT0;
        RD_FULL(1, 1, aA0, aA1, aA2, aA3, b10, b11, b12, b13);
        if (nlast) stB(1, 0, k3);
        SBAR;
        MM16(4, aB0, aB1, aB2, aB3, b00, b01, b02, b03);
        ENDPH;
        // P7: compute (aA,b1) rows0-3; read half(1,1)->aB; stage A10(k3)
        WAIT0;
        RD_HALF(1, 1, aB0, aB1, aB2, aB3);
        if (nlast) stA(1, 0, k3);
        SBAR;
        if (nlast) { asm volatile("s_waitcnt vmcnt(8)"); SBAR; }
        MM16(0, aA0, aA1, aA2, aA3, b10, b11, b12, b13);
        ENDPH;
        // P8: compute (aB,b1) rows4-7; read full(0,0)->aA,b0 (next); stage B11(k3)
        WAIT0;
        if (nlast) {
            RD_FULL(0, 0, aA0, aA1, aA2, aA3, b00, b01, b02, b03);
            stB(1, 1, k3);
        }
        SBAR;
        MM16(4, aB0, aB1, aB2, aB3, b10, b11, b12, b13);
        ENDPH;
    }
#undef RD_FULL
#undef RD_HALF
#undef MM16
}

// ---------------- fused GEMM1+2 + elementwise epilogue (bf16 a,u out) -------
__global__ __launch_bounds__(512, 2)
void k_gemm_fused(const bf16_t* __restrict__ A, const bf16_t* __restrict__ Wcat,
                  const float* __restrict__ x, const float* __restrict__ b_dt,
                  const float* __restrict__ negA,
                  unsigned short* __restrict__ abuf, unsigned short* __restrict__ ubuf) {
    __shared__ __align__(16) bf16_t As[4 * HT_ELEMS];
    __shared__ __align__(16) bf16_t Bs[4 * HT_ELEMS];

    const int tid  = threadIdx.x;
    const int lane = tid & 63;
    const int wave = tid >> 6;
    const int wm   = wave >> 2;      // 0..1
    const int wn   = wave & 3;       // 0..3
    int flat = blockIdx.x;
    int swzb = (flat & 7) * 64 + (flat >> 3);
    int bm = swzb & 31;
    int bn = swzb >> 5;

    f32x4 acc[8][4];
#pragma unroll
    for (int i = 0; i < 8; i++)
#pragma unroll
        for (int j = 0; j < 4; j++) acc[i][j] = (f32x4){0.f, 0.f, 0.f, 0.f};

    gemm256_main<DIM / 64>(A, Wcat, DIM, (long)bm * 256, (long)bn * 256,
                           As, Bs, acc, wave, lane, wm, wn);

    const int l15  = lane & 15;
    const int quad = lane >> 4;
    const int odd  = l15 & 1;
#pragma unroll
    for (int i = 0; i < 8; i++) {
#pragma unroll
        for (int j = 0; j < 4; j++) {
#pragma unroll
            for (int r = 0; r < 4; r++) {
                float v = acc[i][j][r];
                float w = __shfl_xor(v, 1);
                float dtpre = odd ? w : v;
                float bpv   = odd ? v : w;
                long row = (long)bm * 256 + wm * 128 + i * 16 + quad * 4 + r;
                int  col = bn * 256 + wn * 64 + j * 16 + l15;
                int  n   = col >> 1;
                float z  = dtpre + b_dt[n];
                float dt = (z > 15.f) ? z : __logf(1.f + __expf(z)); // softplus
                float a  = __expf(negA[n] * dt);                     // A_bar
                float u  = dt * bpv * x[row * DIM + n];              // dt*Bp*x
                long idx = row * DIM + n;
                if (odd) ubuf[idx] = f2bf_rne(u); else abuf[idx] = f2bf_rne(a);
            }
        }
    }
}

// ---------------- plain NT-GEMM: out = h*W_C^T + skip*x ----------------
__global__ __launch_bounds__(512, 2)
void k_gemm_bt(const bf16_t* __restrict__ A, const bf16_t* __restrict__ Bm,
               float* __restrict__ C, int N, int K,
               const float* __restrict__ skip, const float* __restrict__ xres) {
    __shared__ __align__(16) bf16_t As[4 * HT_ELEMS];
    __shared__ __align__(16) bf16_t Bs[4 * HT_ELEMS];

    const int tid  = threadIdx.x;
    const int lane = tid & 63;
    const int wave = tid >> 6;
    const int wm   = wave >> 2;
    const int wn   = wave & 3;
    int flat = blockIdx.x;
    int swzb = (flat & 7) * 32 + (flat >> 3);
    int bm = swzb & 31;
    int bn = swzb >> 5;

    f32x4 acc[8][4];
#pragma unroll
    for (int i = 0; i < 8; i++)
#pragma unroll
        for (int j = 0; j < 4; j++) acc[i][j] = (f32x4){0.f, 0.f, 0.f, 0.f};

    gemm256_main<DIM / 64>(A, Bm, K, (long)bm * 256, (long)bn * 256,
                           As, Bs, acc, wave, lane, wm, wn);

    const int l15  = lane & 15;
    const int quad = lane >> 4;
#pragma unroll
    for (int i = 0; i < 8; i++) {
#pragma unroll
        for (int j = 0; j < 4; j++) {
#pragma unroll
            for (int r = 0; r < 4; r++) {
                long row = (long)bm * 256 + wm * 128 + i * 16 + quad * 4 + r;
                long col = (long)bn * 256 + wn * 64 + j * 16 + l15;
                long idx = row * (long)N + col;
                float v = acc[i][j][r];
                if (skip) v += skip[col] * xres[idx];
                C[idx] = v;
            }
        }
    }
}

// ---------------- chunked scan on bf16 a,u (2 channels per thread) ----------
__global__ void k_scan1(const unsigned short* __restrict__ a,
                        const unsigned short* __restrict__ u,
                        float* __restrict__ P, float* __restrict__ V) {
    int t  = blockIdx.x * blockDim.x + threadIdx.x;
    int n2 = t & (DIM / 2 - 1);
    int c  = (t >> 10) & (CHUNKS - 1);
    int b  = t >> (10 + CSH);
    long base = ((long)b * SEQ + (long)c * CLEN) * DIM + n2 * 2;
    float p0 = 1.f, v0 = 0.f, p1 = 1.f, v1 = 0.f;
    for (int s = 0; s < CLEN; s++) {
        u16x2 av = *(const u16x2*)(a + base + (long)s * DIM);
        u16x2 uv = *(const u16x2*)(u + base + (long)s * DIM);
        float a0 = bf2f(av[0]), a1 = bf2f(av[1]);
        v0 = a0 * v0 + bf2f(uv[0]);  p0 *= a0;
        v1 = a1 * v1 + bf2f(uv[1]);  p1 *= a1;
    }
    long pidx = ((long)b * CHUNKS + c) * DIM + n2 * 2;
    *(float2*)(P + pidx) = make_float2(p0, p1);
    *(float2*)(V + pidx) = make_float2(v0, v1);
}

__global__ void k_scan2(const float* __restrict__ P, const float* __restrict__ V,
                        float* __restrict__ carry) {
    int t = blockIdx.x * blockDim.x + threadIdx.x;   // B*N
    int n = t & (DIM - 1);
    int b = t >> 11;
    float H = 0.f;
    for (int c = 0; c < CHUNKS; c++) {
        long idx = ((long)b * CHUNKS + c) * DIM + n;
        carry[idx] = H;
        H = P[idx] * H + V[idx];
    }
}

__global__ void k_scan3(const unsigned short* __restrict__ a,
                        const unsigned short* __restrict__ u,
                        const float* __restrict__ carry,
                        unsigned short* __restrict__ h) {
    int t  = blockIdx.x * blockDim.x + threadIdx.x;
    int n2 = t & (DIM / 2 - 1);
    int c  = (t >> 10) & (CHUNKS - 1);
    int b  = t >> (10 + CSH);
    long base = ((long)b * SEQ + (long)c * CLEN) * DIM + n2 * 2;
    long cidx = ((long)b * CHUNKS + c) * DIM + n2 * 2;
    float2 Hc = *(const float2*)(carry + cidx);
    float H0 = Hc.x, H1 = Hc.y;
    for (int s = 0; s < CLEN; s++) {
        u16x2 av = *(const u16x2*)(a + base + (long)s * DIM);
        u16x2 uv = *(const u16x2*)(u + base + (long)s * DIM);
        H0 = bf2f(av[0]) * H0 + bf2f(uv[0]);
        H1 = bf2f(av[1]) * H1 + bf2f(uv[1]);
        u16x2 o; o[0] = f2bf_rne(H0); o[1] = f2bf_rne(H1);
        *(u16x2*)(h + base + (long)s * DIM) = o;
    }
}

extern "C" void kernel_launch(void* const* d_in, const int* in_sizes, int n_in,
                              void* d_out, int out_size, void* d_ws, size_t ws_size,
                              hipStream_t stream) {
    const float* x      = (const float*)d_in[0];
    const float* W_dt   = (const float*)d_in[1];
    const float* b_dt   = (const float*)d_in[2];
    const float* W_B    = (const float*)d_in[3];
    const float* W_C    = (const float*)d_in[4];
    const float* A_log  = (const float*)d_in[5];
    const float* D_skip = (const float*)d_in[6];
    float* out = (float*)d_out;

    char* ws = (char*)d_ws;
    size_t off = 0;
    auto alloc = [&](size_t bytes) -> char* {
        char* p = ws + off;
        off += (bytes + 255) & ~(size_t)255;
        return p;
    };
    unsigned short* xb   = (unsigned short*)alloc((size_t)MTOT * DIM * 2); // reused as h_bf
    unsigned short* wcat = (unsigned short*)alloc((size_t)2 * DIM * DIM * 2);
    unsigned short* wcb  = (unsigned short*)alloc((size_t)DIM * DIM * 2);
    unsigned short* abuf = (unsigned short*)alloc((size_t)MTOT * DIM * 2);  // bf16 a
    unsigned short* ubuf = (unsigned short*)alloc((size_t)MTOT * DIM * 2);  // bf16 u
    float* P     = (float*)alloc((size_t)NBATCH * CHUNKS * DIM * 4);
    float* V     = (float*)alloc((size_t)NBATCH * CHUNKS * DIM * 4);
    float* carry = (float*)alloc((size_t)NBATCH * CHUNKS * DIM * 4);
    float* negA  = (float*)alloc((size_t)DIM * 4);

    const int n4x = MTOT * DIM / 4;
    const int n4w = DIM * DIM / 4;
    k_convert<<<n4x / 256, 256, 0, stream>>>(x, xb, n4x);
    k_convert_ilv<<<n4w / 256, 256, 0, stream>>>(W_dt, wcat, n4w, 0);
    k_convert_ilv<<<n4w / 256, 256, 0, stream>>>(W_B,  wcat, n4w, 1);
    k_convert<<<n4w / 256, 256, 0, stream>>>(W_C, wcb, n4w);
    k_prep_a<<<DIM / 256, 256, 0, stream>>>(A_log, negA, DIM);

    // fused GEMM1+2 + elementwise: M=8192, N=4096, K=2048; 256^2 tiles
    k_gemm_fused<<<(MTOT / 256) * (2 * DIM / 256), 512, 0, stream>>>(
        (const bf16_t*)xb, (const bf16_t*)wcat, x, b_dt, negA, abuf, ubuf);

    const int scan_threads = NBATCH * CHUNKS * DIM / 2;   // 131072
    k_scan1<<<scan_threads / 256, 256, 0, stream>>>(abuf, ubuf, P, V);
    k_scan2<<<(NBATCH * DIM) / 256, 256, 0, stream>>>(P, V, carry);
    k_scan3<<<scan_threads / 256, 256, 0, stream>>>(abuf, ubuf, carry, xb /* h_bf */);

    // out = h * W_C^T + D_skip * x : M=8192, N=2048, K=2048; 256^2 tiles
    k_gemm_bt<<<(MTOT / 256) * (DIM / 256), 512, 0, stream>>>(
        (const bf16_t*)xb, (const bf16_t*)wcb, out, DIM, DIM, D_skip, x);
}

// Round 7
// 488.970 us; speedup vs baseline: 1.0977x; 1.0977x over previous
//
#include <hip/hip_runtime.h>

#define SEQ    2048
#define DIM    2048              // D == N
#define NBATCH 4
#define MTOT   (NBATCH * SEQ)    // 8192
#define CHUNKS 32
#define CLEN   (SEQ / CHUNKS)    // 64
#define CSH    5                 // log2(CHUNKS)
#define HT_ELEMS (256 * 32)      // one staged K-half tile: 256 rows x 32 cols (16 KB)

typedef __bf16 bf16_t;
typedef __bf16 bf16x8 __attribute__((ext_vector_type(8)));
typedef float  f32x4  __attribute__((ext_vector_type(4)));
typedef unsigned short u16x4 __attribute__((ext_vector_type(4)));
typedef unsigned short u16x2 __attribute__((ext_vector_type(2)));

typedef __attribute__((address_space(3))) bf16_t lds_bf16;

__device__ __forceinline__ unsigned short f2bf_rne(float f) {
    unsigned int u = __float_as_uint(f);
    u += 0x7fffu + ((u >> 16) & 1u);
    return (unsigned short)(u >> 16);
}
__device__ __forceinline__ float bf2f(unsigned short v) {
    return __uint_as_float((unsigned int)v << 16);
}

// ---------------- fused prep: all fp32->bf16 converts + negA in ONE launch --
// Regions (all multiples of 256 -> block-uniform branches):
//   [0, n4x)            x -> xb            (f32x4 -> u16x4)
//   [n4x, +n4w)         W_dt -> wcat row 2n+0
//   [.., +n4w)          W_B  -> wcat row 2n+1
//   [.., +n4w)          W_C  -> wcb
//   [.., +DIM/4)        negA = -exp(A_log)
__global__ void k_prep_all(const float* __restrict__ x, const float* __restrict__ W_dt,
                           const float* __restrict__ W_B, const float* __restrict__ W_C,
                           const float* __restrict__ A_log,
                           unsigned short* __restrict__ xb, unsigned short* __restrict__ wcat,
                           unsigned short* __restrict__ wcb, float* __restrict__ negA) {
    const int n4x = MTOT * DIM / 4;
    const int n4w = DIM * DIM / 4;
    int i = blockIdx.x * blockDim.x + threadIdx.x;
    if (i < n4x) {
        f32x4 v = ((const f32x4*)x)[i];
        u16x4 o;
        o[0] = f2bf_rne(v[0]); o[1] = f2bf_rne(v[1]);
        o[2] = f2bf_rne(v[2]); o[3] = f2bf_rne(v[3]);
        ((u16x4*)xb)[i] = o;
        return;
    }
    i -= n4x;
    if (i < 2 * n4w) {                       // W_dt (phase 0) or W_B (phase 1)
        int phase = (i >= n4w);
        int j = phase ? i - n4w : i;
        const float* src = phase ? W_B : W_dt;
        const int R4 = DIM / 4;
        int nrow = j / R4;
        int dcol = j - nrow * R4;
        f32x4 v = ((const f32x4*)src)[j];
        u16x4 o;
        o[0] = f2bf_rne(v[0]); o[1] = f2bf_rne(v[1]);
        o[2] = f2bf_rne(v[2]); o[3] = f2bf_rne(v[3]);
        ((u16x4*)wcat)[(2 * nrow + phase) * R4 + dcol] = o;
        return;
    }
    i -= 2 * n4w;
    if (i < n4w) {
        f32x4 v = ((const f32x4*)W_C)[i];
        u16x4 o;
        o[0] = f2bf_rne(v[0]); o[1] = f2bf_rne(v[1]);
        o[2] = f2bf_rne(v[2]); o[3] = f2bf_rne(v[3]);
        ((u16x4*)wcb)[i] = o;
        return;
    }
    i -= n4w;
    if (i < DIM / 4) {
        f32x4 v = ((const f32x4*)A_log)[i];
        f32x4 o;
        o[0] = -__expf(v[0]); o[1] = -__expf(v[1]);
        o[2] = -__expf(v[2]); o[3] = -__expf(v[3]);
        ((f32x4*)negA)[i] = o;
    }
}

// ---------------- staging: 16B global_load_lds, XOR-swizzled chunks ----------
// Per-thread global base and LDS dst base are HOISTED out of the K-loop;
// per-call cost is one 32-bit offset add (was: 2x 64-bit row*K mul + adds).
__device__ __forceinline__ void stage_half(const bf16_t* __restrict__ gbase, int K,
                                           int k0, char* ldsbase) {
#pragma unroll
    for (int q = 0; q < 2; q++) {
        __builtin_amdgcn_global_load_lds(
            (const __attribute__((address_space(1))) void*)(gbase + (long)q * 16 * K + k0),
            (__attribute__((address_space(3))) void*)(ldsbase + q * 1024),
            16, 0, 0);
    }
}

#define MFMA_B16(a, b, c) __builtin_amdgcn_mfma_f32_16x16x32_bf16(a, b, c, 0, 0, 0)
#define BAR  __builtin_amdgcn_s_barrier()
#define SBAR __builtin_amdgcn_sched_barrier(0)
#define DSR(D, P) asm volatile("ds_read_b128 %0, %1" : "=v"(D) : "v"(P))

// ---------------- GEMM core: 256x256 tile, BK=64, 8-phase schedule -----------
// (round-4 state: best measured. Raw barriers, bare waitcnts, SBAR pins,
//  inline-asm ds_read, counted vmcnt(6) at P4/P8 only.)
template <int KTILES>   // number of 64-wide K tiles (K/64), must be even
__device__ __forceinline__ void gemm256_main(const bf16_t* __restrict__ A,
                                             const bf16_t* __restrict__ Bm,
                                             int K, long arow0, long brow0,
                                             bf16_t* As, bf16_t* Bs,
                                             f32x4 acc[8][4],
                                             int wave, int lane, int wm, int wn) {
    const int l15  = lane & 15;
    const int quad = lane >> 4;
    const int swz  = (quad ^ ((l15 >> 1) & 3)) * 8;
    const int aoff = (wm * 128 + l15) * 32 + swz;
    const int boff = (wn * 64  + l15) * 32 + swz;

    const lds_bf16* Aw = ((const lds_bf16*)As) + aoff;
    const lds_bf16* Bw = ((const lds_bf16*)Bs) + boff;

    // hoisted staging bases
    const int rl     = lane >> 2;
    const int gchunk = (lane & 3) ^ ((lane >> 3) & 3);
    const bf16_t* gA = A  + (arow0 + wave * 32 + rl) * (long)K + gchunk * 8;
    const bf16_t* gB = Bm + (brow0 + wave * 32 + rl) * (long)K + gchunk * 8;
    char* ldsA = (char*)As + wave * 2048;
    char* ldsB = (char*)Bs + wave * 2048;

    auto stA = [&](int buf, int ks, int kt) {
        stage_half(gA, K, kt * 64 + ks * 32, ldsA + (buf * 2 + ks) * (HT_ELEMS * 2));
    };
    auto stB = [&](int buf, int ks, int kt) {
        stage_half(gB, K, kt * 64 + ks * 32, ldsB + (buf * 2 + ks) * (HT_ELEMS * 2));
    };

    // prologue: stage 7 of 8 slots (A11 is staged at P1 of iter 0).
    stB(0, 0, 0); stA(0, 0, 0); stB(0, 1, 0); stA(0, 1, 0);
    stB(1, 0, 1); stA(1, 0, 1); stB(1, 1, 1);
    asm volatile("s_waitcnt vmcnt(6)");
    SBAR;
    BAR;

    bf16x8 a0, a1, a2, a3, b0, b1, b2, b3;

#define LDAB03(BUF, KS) { \
    const lds_bf16* pa = Aw + ((BUF) * 2 + (KS)) * HT_ELEMS; \
    const lds_bf16* pb = Bw + ((BUF) * 2 + (KS)) * HT_ELEMS; \
    DSR(a0, pa);        DSR(b0, pb); \
    DSR(a1, pa + 512);  DSR(b1, pb + 512); \
    DSR(a2, pa + 1024); DSR(b2, pb + 1024); \
    DSR(a3, pa + 1536); DSR(b3, pb + 1536); }
#define LDA47(BUF, KS) { \
    const lds_bf16* pa = Aw + ((BUF) * 2 + (KS)) * HT_ELEMS + 2048; \
    DSR(a0, pa); DSR(a1, pa + 512); DSR(a2, pa + 1024); DSR(a3, pa + 1536); }
#define MM16(I0) \
    SBAR; \
    BAR; \
    asm volatile("s_waitcnt lgkmcnt(0)"); \
    SBAR; \
    __builtin_amdgcn_s_setprio(1); \
    acc[(I0)+0][0] = MFMA_B16(a0, b0, acc[(I0)+0][0]); \
    acc[(I0)+0][1] = MFMA_B16(a0, b1, acc[(I0)+0][1]); \
    acc[(I0)+0][2] = MFMA_B16(a0, b2, acc[(I0)+0][2]); \
    acc[(I0)+0][3] = MFMA_B16(a0, b3, acc[(I0)+0][3]); \
    acc[(I0)+1][0] = MFMA_B16(a1, b0, acc[(I0)+1][0]); \
    acc[(I0)+1][1] = MFMA_B16(a1, b1, acc[(I0)+1][1]); \
    acc[(I0)+1][2] = MFMA_B16(a1, b2, acc[(I0)+1][2]); \
    acc[(I0)+1][3] = MFMA_B16(a1, b3, acc[(I0)+1][3]); \
    acc[(I0)+2][0] = MFMA_B16(a2, b0, acc[(I0)+2][0]); \
    acc[(I0)+2][1] = MFMA_B16(a2, b1, acc[(I0)+2][1]); \
    acc[(I0)+2][2] = MFMA_B16(a2, b2, acc[(I0)+2][2]); \
    acc[(I0)+2][3] = MFMA_B16(a2, b3, acc[(I0)+2][3]); \
    acc[(I0)+3][0] = MFMA_B16(a3, b0, acc[(I0)+3][0]); \
    acc[(I0)+3][1] = MFMA_B16(a3, b1, acc[(I0)+3][1]); \
    acc[(I0)+3][2] = MFMA_B16(a3, b2, acc[(I0)+3][2]); \
    acc[(I0)+3][3] = MFMA_B16(a3, b3, acc[(I0)+3][3]); \
    __builtin_amdgcn_s_setprio(0); \
    SBAR; \
    BAR;

#pragma unroll 1
    for (int t = 0; t < KTILES / 2; ++t) {
        const bool nlast = (t != KTILES / 2 - 1);
        const int k1 = 2 * t + 1, k2 = 2 * t + 2, k3 = 2 * t + 3;
        // P1
        LDAB03(0, 0);
        stA(1, 1, k1);
        MM16(0);
        // P2
        LDA47(0, 0);
        if (nlast) stB(0, 0, k2);
        MM16(4);
        // P3
        LDAB03(0, 1);
        if (nlast) stA(0, 0, k2);
        MM16(0);
        // P4 (+ counted vmcnt)
        LDA47(0, 1);
        if (nlast) stB(0, 1, k2);
        if (nlast) { asm volatile("s_waitcnt vmcnt(6)"); }
        else       { asm volatile("s_waitcnt vmcnt(0)"); }
        MM16(4);
        // P5
        LDAB03(1, 0);
        if (nlast) stA(0, 1, k2);
        MM16(0);
        // P6
        LDA47(1, 0);
        if (nlast) stB(1, 0, k3);
        MM16(4);
        // P7
        LDAB03(1, 1);
        if (nlast) stA(1, 0, k3);
        MM16(0);
        // P8 (+ counted vmcnt)
        LDA47(1, 1);
        if (nlast) stB(1, 1, k3);
        if (nlast) { asm volatile("s_waitcnt vmcnt(6)"); }
        MM16(4);
    }
#undef LDAB03
#undef LDA47
#undef MM16
}

// ---------------- fused GEMM1+2 + elementwise epilogue (bf16 a,u out) -------
__global__ __launch_bounds__(512, 2)
void k_gemm_fused(const bf16_t* __restrict__ A, const bf16_t* __restrict__ Wcat,
                  const float* __restrict__ x, const float* __restrict__ b_dt,
                  const float* __restrict__ negA,
                  unsigned short* __restrict__ abuf, unsigned short* __restrict__ ubuf) {
    __shared__ __align__(16) bf16_t As[4 * HT_ELEMS];
    __shared__ __align__(16) bf16_t Bs[4 * HT_ELEMS];

    const int tid  = threadIdx.x;
    const int lane = tid & 63;
    const int wave = tid >> 6;
    const int wm   = wave >> 2;      // 0..1
    const int wn   = wave & 3;       // 0..3
    int flat = blockIdx.x;
    int swzb = (flat & 7) * 64 + (flat >> 3);
    int bm = swzb & 31;
    int bn = swzb >> 5;

    f32x4 acc[8][4];
#pragma unroll
    for (int i = 0; i < 8; i++)
#pragma unroll
        for (int j = 0; j < 4; j++) acc[i][j] = (f32x4){0.f, 0.f, 0.f, 0.f};

    gemm256_main<DIM / 64>(A, Wcat, DIM, (long)bm * 256, (long)bn * 256,
                           As, Bs, acc, wave, lane, wm, wn);

    const int l15  = lane & 15;
    const int quad = lane >> 4;
    const int odd  = l15 & 1;
#pragma unroll
    for (int i = 0; i < 8; i++) {
#pragma unroll
        for (int j = 0; j < 4; j++) {
#pragma unroll
            for (int r = 0; r < 4; r++) {
                float v = acc[i][j][r];
                float w = __shfl_xor(v, 1);
                float dtpre = odd ? w : v;
                float bpv   = odd ? v : w;
                long row = (long)bm * 256 + wm * 128 + i * 16 + quad * 4 + r;
                int  col = bn * 256 + wn * 64 + j * 16 + l15;
                int  n   = col >> 1;
                float z  = dtpre + b_dt[n];
                float dt = (z > 15.f) ? z : __logf(1.f + __expf(z)); // softplus
                float a  = __expf(negA[n] * dt);                     // A_bar
                float u  = dt * bpv * x[row * DIM + n];              // dt*Bp*x
                long idx = row * DIM + n;
                if (odd) ubuf[idx] = f2bf_rne(u); else abuf[idx] = f2bf_rne(a);
            }
        }
    }
}

// ---------------- plain NT-GEMM: out = h*W_C^T + skip*x ----------------
__global__ __launch_bounds__(512, 2)
void k_gemm_bt(const bf16_t* __restrict__ A, const bf16_t* __restrict__ Bm,
               float* __restrict__ C, int N, int K,
               const float* __restrict__ skip, const float* __restrict__ xres) {
    __shared__ __align__(16) bf16_t As[4 * HT_ELEMS];
    __shared__ __align__(16) bf16_t Bs[4 * HT_ELEMS];

    const int tid  = threadIdx.x;
    const int lane = tid & 63;
    const int wave = tid >> 6;
    const int wm   = wave >> 2;
    const int wn   = wave & 3;
    int flat = blockIdx.x;
    int swzb = (flat & 7) * 32 + (flat >> 3);
    int bm = swzb & 31;
    int bn = swzb >> 5;

    f32x4 acc[8][4];
#pragma unroll
    for (int i = 0; i < 8; i++)
#pragma unroll
        for (int j = 0; j < 4; j++) acc[i][j] = (f32x4){0.f, 0.f, 0.f, 0.f};

    gemm256_main<DIM / 64>(A, Bm, K, (long)bm * 256, (long)bn * 256,
                           As, Bs, acc, wave, lane, wm, wn);

    const int l15  = lane & 15;
    const int quad = lane >> 4;
#pragma unroll
    for (int i = 0; i < 8; i++) {
#pragma unroll
        for (int j = 0; j < 4; j++) {
#pragma unroll
            for (int r = 0; r < 4; r++) {
                long row = (long)bm * 256 + wm * 128 + i * 16 + quad * 4 + r;
                long col = (long)bn * 256 + wn * 64 + j * 16 + l15;
                long idx = row * (long)N + col;
                float v = acc[i][j][r];
                if (skip) v += skip[col] * xres[idx];
                C[idx] = v;
            }
        }
    }
}

// ---------------- chunked scan on bf16 a,u (2 channels per thread) ----------
__global__ void k_scan1(const unsigned short* __restrict__ a,
                        const unsigned short* __restrict__ u,
                        float* __restrict__ P, float* __restrict__ V) {
    int t  = blockIdx.x * blockDim.x + threadIdx.x;
    int n2 = t & (DIM / 2 - 1);
    int c  = (t >> 10) & (CHUNKS - 1);
    int b  = t >> (10 + CSH);
    long base = ((long)b * SEQ + (long)c * CLEN) * DIM + n2 * 2;
    float p0 = 1.f, v0 = 0.f, p1 = 1.f, v1 = 0.f;
    for (int s = 0; s < CLEN; s++) {
        u16x2 av = *(const u16x2*)(a + base + (long)s * DIM);
        u16x2 uv = *(const u16x2*)(u + base + (long)s * DIM);
        float a0 = bf2f(av[0]), a1 = bf2f(av[1]);
        v0 = a0 * v0 + bf2f(uv[0]);  p0 *= a0;
        v1 = a1 * v1 + bf2f(uv[1]);  p1 *= a1;
    }
    long pidx = ((long)b * CHUNKS + c) * DIM + n2 * 2;
    *(float2*)(P + pidx) = make_float2(p0, p1);
    *(float2*)(V + pidx) = make_float2(v0, v1);
}

__global__ void k_scan2(const float* __restrict__ P, const float* __restrict__ V,
                        float* __restrict__ carry) {
    int t = blockIdx.x * blockDim.x + threadIdx.x;   // B*N
    int n = t & (DIM - 1);
    int b = t >> 11;
    float H = 0.f;
    for (int c = 0; c < CHUNKS; c++) {
        long idx = ((long)b * CHUNKS + c) * DIM + n;
        carry[idx] = H;
        H = P[idx] * H + V[idx];
    }
}

__global__ void k_scan3(const unsigned short* __restrict__ a,
                        const unsigned short* __restrict__ u,
                        const float* __restrict__ carry,
                        unsigned short* __restrict__ h) {
    int t  = blockIdx.x * blockDim.x + threadIdx.x;
    int n2 = t & (DIM / 2 - 1);
    int c  = (t >> 10) & (CHUNKS - 1);
    int b  = t >> (10 + CSH);
    long base = ((long)b * SEQ + (long)c * CLEN) * DIM + n2 * 2;
    long cidx = ((long)b * CHUNKS + c) * DIM + n2 * 2;
    float2 Hc = *(const float2*)(carry + cidx);
    float H0 = Hc.x, H1 = Hc.y;
    for (int s = 0; s < CLEN; s++) {
        u16x2 av = *(const u16x2*)(a + base + (long)s * DIM);
        u16x2 uv = *(const u16x2*)(u + base + (long)s * DIM);
        H0 = bf2f(av[0]) * H0 + bf2f(uv[0]);
        H1 = bf2f(av[1]) * H1 + bf2f(uv[1]);
        u16x2 o; o[0] = f2bf_rne(H0); o[1] = f2bf_rne(H1);
        *(u16x2*)(h + base + (long)s * DIM) = o;
    }
}

extern "C" void kernel_launch(void* const* d_in, const int* in_sizes, int n_in,
                              void* d_out, int out_size, void* d_ws, size_t ws_size,
                              hipStream_t stream) {
    const float* x      = (const float*)d_in[0];
    const float* W_dt   = (const float*)d_in[1];
    const float* b_dt   = (const float*)d_in[2];
    const float* W_B    = (const float*)d_in[3];
    const float* W_C    = (const float*)d_in[4];
    const float* A_log  = (const float*)d_in[5];
    const float* D_skip = (const float*)d_in[6];
    float* out = (float*)d_out;

    char* ws = (char*)d_ws;
    size_t off = 0;
    auto alloc = [&](size_t bytes) -> char* {
        char* p = ws + off;
        off += (bytes + 255) & ~(size_t)255;
        return p;
    };
    unsigned short* xb   = (unsigned short*)alloc((size_t)MTOT * DIM * 2); // reused as h_bf
    unsigned short* wcat = (unsigned short*)alloc((size_t)2 * DIM * DIM * 2);
    unsigned short* wcb  = (unsigned short*)alloc((size_t)DIM * DIM * 2);
    unsigned short* abuf = (unsigned short*)alloc((size_t)MTOT * DIM * 2);  // bf16 a
    unsigned short* ubuf = (unsigned short*)alloc((size_t)MTOT * DIM * 2);  // bf16 u
    float* P     = (float*)alloc((size_t)NBATCH * CHUNKS * DIM * 4);
    float* V     = (float*)alloc((size_t)NBATCH * CHUNKS * DIM * 4);
    float* carry = (float*)alloc((size_t)NBATCH * CHUNKS * DIM * 4);
    float* negA  = (float*)alloc((size_t)DIM * 4);

    // single fused prep launch (was 5 kernels)
    const int prep_threads = MTOT * DIM / 4 + 3 * (DIM * DIM / 4) + DIM / 4;
    k_prep_all<<<(prep_threads + 255) / 256, 256, 0, stream>>>(
        x, W_dt, W_B, W_C, A_log, xb, wcat, wcb, negA);

    // fused GEMM1+2 + elementwise: M=8192, N=4096, K=2048; 256^2 tiles
    k_gemm_fused<<<(MTOT / 256) * (2 * DIM / 256), 512, 0, stream>>>(
        (const bf16_t*)xb, (const bf16_t*)wcat, x, b_dt, negA, abuf, ubuf);

    const int scan_threads = NBATCH * CHUNKS * DIM / 2;   // 131072
    k_scan1<<<scan_threads / 256, 256, 0, stream>>>(abuf, ubuf, P, V);
    k_scan2<<<(NBATCH * DIM) / 256, 256, 0, stream>>>(P, V, carry);
    k_scan3<<<scan_threads / 256, 256, 0, stream>>>(abuf, ubuf, carry, xb /* h_bf */);

    // out = h * W_C^T + D_skip * x : M=8192, N=2048, K=2048; 256^2 tiles
    k_gemm_bt<<<(MTOT / 256) * (DIM / 256), 512, 0, stream>>>(
        (const bf16_t*)xb, (const bf16_t*)wcb, out, DIM, DIM, D_skip, x);
}